// Round 21
// baseline (98.391 us; speedup 1.0000x reference)
//
#include <hip/hip_runtime.h>
#include <hip/hip_bf16.h>
#include <stdint.h>

// Problem dims (fixed by reference setup_inputs)
#define B_SZ 128
#define R_SZ 36       // real regions per image -- NOT padded (4 imgs = 144 = 9 frags)
#define W_SZ 60       // real words per caption
#define WP_SZ 64      // padded words (dup word 59, masked in epilogue)
#define D_SZ 1024
#define MARGIN 0.2f

#define ATILE_B (144 * 64)        // 9216 B per A K-tile (4 images, unpadded)
#define BTILE_B (256 * 64)        // 16384 B per B K-tile
#define BUFB    (ATILE_B + BTILE_B) // 25600 B; TRIPLE buffer = 76.8 KB -> 2 blocks/CU

typedef __attribute__((ext_vector_type(4))) float f32x4;    // MFMA C/D frag
typedef __attribute__((ext_vector_type(2))) long longx2;    // one b128 = 2 fp8 frags

typedef __attribute__((address_space(3))) unsigned int lds_u32;
typedef const __attribute__((address_space(1))) unsigned int glb_u32;

__device__ __forceinline__ void gload16(const unsigned char* g, unsigned char* l) {
    __builtin_amdgcn_global_load_lds((glb_u32*)g, (lds_u32*)l, 16, 0, 0);
}

// fp32 -> fp8 e4m3 (HW cvt) + K2-INTERLEAVE (validated R14/R15/R20).
// A: 1:1, NO row padding (packed-region layout = original im layout).
// B: word rows padded 60->64 (dup row 59; masked in epilogue).
// Each 64-B K-block of a row stored as [granule g=kgrp][k2][8B]:
//   out byte g*16 + k2*8 + b  <=  original k = k2*32 + g*8 + b.
__global__ __launch_bounds__(256) void convert_fp8_kernel(
        const float* __restrict__ im, const float* __restrict__ s,
        unsigned char* __restrict__ imb, unsigned char* __restrict__ sb) {
    const int nA = B_SZ * R_SZ * 64;      // 294,912 16-B granules of A
    const int nB = B_SZ * WP_SZ * 64;     // 524,288 granules of B
    int i = blockIdx.x * 256 + threadIdx.x;
    const float* srcrow;
    unsigned char* dst;
    int gran;
    if (i < nA) {
        gran = i & 63;
        int row = i >> 6;                 // packed row = j*36 + r (original layout)
        srcrow = im + ((size_t)row << 10);
        dst = imb + (size_t)i * 16;
    } else {
        int i2 = i - nA;
        if (i2 >= nB) return;
        gran = i2 & 63;
        int row = i2 >> 6;
        int j = row >> 6, w = row & 63;
        int ws = w < W_SZ ? w : W_SZ - 1;
        srcrow = s + ((size_t)(j * W_SZ + ws) << 10);
        dst = sb + (size_t)i2 * 16;
    }
    const int kb = gran >> 2, g = gran & 3;
    uint4 o;
    unsigned int* op = (unsigned int*)&o;
#pragma unroll
    for (int q = 0; q < 4; ++q) {
        const int kq = kb * 64 + (q >> 1) * 32 + g * 8 + (q & 1) * 4;
        float4 v = *reinterpret_cast<const float4*>(srcrow + kq);
        int w32 = __builtin_amdgcn_cvt_pk_fp8_f32(v.x, v.y, 0, false);
        w32 = __builtin_amdgcn_cvt_pk_fp8_f32(v.z, v.w, w32, true);
        op[q] = (unsigned int)w32;
    }
    *reinterpret_cast<uint4*>(dst) = o;
}

// Fused GEMM + MISA epilogue, fp8-e4m3, unpadded M (R20) + TRIPLE-buffer
// counted vmcnt (T4, m218): per tile u -- read frags from buf[u%3], stage
// tile u+2 into buf[(u+2)%3] (dead since u-1's barrier), MFMAs, then
// s_waitcnt vmcnt(L) where L = this wave's OWN per-tile stage loads
// (4 for wave 0, 3 for waves 1-7) -> only tile u+2's loads outstanding,
// tile u+1 landed. Loads get ~2 windows of flight; NEVER drained to 0.
// 3 x 25.6 KB = 76.8 KB LDS -> 2 blocks/CU preserved (R17's failure was
// 1 block/CU). All R20-validated pieces verbatim: zero-conflict quarter-wave
// swizzle, k2-interleaved b128 frags, 1Mx8N wave split (acc[9][2]),
// boundary-aware epilogue, supertile XCD swizzle.
__global__ __launch_bounds__(512, 4) void scores_kernel(
        const unsigned char* __restrict__ imb,    // [4608][1024] fp8 interleaved
        const unsigned char* __restrict__ sbp,    // [128][64][1024] fp8 interleaved
        const int* __restrict__ s_l,
        float* __restrict__ S)                    // [j][i]
{
    __shared__ __align__(16) unsigned char LDS[3 * BUFB];   // 76.8 KB
    __shared__ float red2[8][4];

    const int tid  = threadIdx.x;
    const int wc   = tid >> 6;        // 0..7 (N-split only)
    const int lane = tid & 63;
    const int l15  = lane & 15;
    const int kgrp = lane >> 4;       // 0..3

    // Supertile XCD swizzle (R10-validated)
    int bid = blockIdx.x;
    int k8  = bid & 7;                // XCD
    int w   = bid >> 3;               // 0..127 within XCD
    int jtg = w >> 5;                 // 0..3
    int sw  = w & 31;
    int it  = k8 * 4 + (sw >> 3);     // 0..31 (4 captions each)
    int jt  = jtg * 8 + (sw & 7);     // 0..31 (4 images = 144 packed rows each)

    // staging: chunk = 16 rows x 64 B; row-in-chunk = lane>>2, dest granule lane&3;
    // source granule = (lane&3) ^ h(row), h(row) = (row>>1)&3 = (lane>>3)&3
    const int drow = lane >> 2;
    const int sgr  = ((lane & 3) ^ ((lane >> 3) & 3)) * 16;

    // 25 1-KB chunks (A:9, B:16); wave w stages chunks {w, w+8, w+16, w+24} (c<25)
    // -> wave 0 has 4 chunks, waves 1-7 have 3 (L for the counted vmcnt).
    const unsigned char* gsrc[4];
    int ldso[4];
#pragma unroll
    for (int si = 0; si < 4; ++si) {
        int c = wc + si * 8;
        if (c < 9) {          // A chunk: packed rows jt*144 + c*16 + drow
            gsrc[si] = imb + (size_t)(jt * 144 + c * 16 + drow) * 1024 + sgr;
            ldso[si] = c * 1024 + lane * 16;
        } else if (c < 25) {  // B chunk
            int b = c - 9;
            gsrc[si] = sbp + (size_t)(it * 256 + b * 16 + drow) * 1024 + sgr;
            ldso[si] = ATILE_B + b * 1024 + lane * 16;
        }
    }

    // ds_read addressing: row*64 + (kgrp ^ ((row>>1)&3))*16 (R15 zero-conflict)
    const int slot0 = (kgrp ^ ((l15 >> 1) & 3)) * 16;
    const int abase = l15 * 64 + slot0;               // + rf*1024
    int bbase[2];
#pragma unroll
    for (int cf = 0; cf < 2; ++cf)
        bbase[cf] = ATILE_B + (wc * 32 + cf * 16 + l15) * 64 + slot0;

    f32x4 acc[9][2] = {};

    // prologue: stage tile 0 -> buf0, tile 1 -> buf1; counted wait (tile 0 in)
#pragma unroll
    for (int si = 0; si < 4; ++si) {
        int c = wc + si * 8;
        if (c < 25) gload16(gsrc[si], LDS + ldso[si]);
    }
#pragma unroll
    for (int si = 0; si < 4; ++si) {
        int c = wc + si * 8;
        if (c < 25) gload16(gsrc[si] + 64, LDS + BUFB + ldso[si]);
    }
    if (wc == 0) { asm volatile("s_waitcnt vmcnt(4)" ::: "memory"); }
    else         { asm volatile("s_waitcnt vmcnt(3)" ::: "memory"); }
    __builtin_amdgcn_s_barrier();

    // main loop: tiles 0..14 (5 groups x 3, static buffer indices), tile 15 tail
#pragma unroll 1
    for (int g = 0; g < 5; ++g) {
#pragma unroll
        for (int s3 = 0; s3 < 3; ++s3) {
            const int u = g * 3 + s3;
            const unsigned char* base = LDS + s3 * BUFB;          // u % 3 == s3
            unsigned char* dstb = LDS + ((s3 + 2) % 3) * BUFB;    // (u+2) % 3

            // B frags for this wave's 32 cols: 2 ds_read_b128
            longx2 bfr[2];
#pragma unroll
            for (int cf = 0; cf < 2; ++cf)
                bfr[cf] = *reinterpret_cast<const longx2*>(base + bbase[cf]);

            // stage tile u+2 (clamped; redundant tail stages keep counts uniform)
            {
                const int ko = (u + 2 < 16 ? u + 2 : 15) * 64;
#pragma unroll
                for (int si = 0; si < 4; ++si) {
                    int c = wc + si * 8;
                    if (c < 25) gload16(gsrc[si] + ko, dstb + ldso[si]);
                }
            }

            // A streamed per rf: 1 ds_read_b128 + 4 MFMAs
            __builtin_amdgcn_s_setprio(1);
#pragma unroll
            for (int rf = 0; rf < 9; ++rf) {
                longx2 af = *reinterpret_cast<const longx2*>(base + abase + rf * 1024);
#pragma unroll
                for (int k2 = 0; k2 < 2; ++k2)
#pragma unroll
                    for (int cf = 0; cf < 2; ++cf)
                        acc[rf][cf] = __builtin_amdgcn_mfma_f32_16x16x32_fp8_fp8(
                            af[k2], bfr[cf][k2], acc[rf][cf], 0, 0, 0);
            }
            __builtin_amdgcn_s_setprio(0);

            // counted rendezvous: only tile u+2's own L loads outstanding
            // -> tile u+1 landed; loads never drained to 0 (T4/m218)
            if (wc == 0) { asm volatile("s_waitcnt vmcnt(4)" ::: "memory"); }
            else         { asm volatile("s_waitcnt vmcnt(3)" ::: "memory"); }
            __builtin_amdgcn_s_barrier();
        }
    }
    {   // tail: tile 15 (buf 15%3 == 0), no stage/sync after
        const unsigned char* base = LDS;
        longx2 bfr[2];
#pragma unroll
        for (int cf = 0; cf < 2; ++cf)
            bfr[cf] = *reinterpret_cast<const longx2*>(base + bbase[cf]);
        __builtin_amdgcn_s_setprio(1);
#pragma unroll
        for (int rf = 0; rf < 9; ++rf) {
            longx2 af = *reinterpret_cast<const longx2*>(base + abase + rf * 1024);
#pragma unroll
            for (int k2 = 0; k2 < 2; ++k2)
#pragma unroll
                for (int cf = 0; cf < 2; ++cf)
                    acc[rf][cf] = __builtin_amdgcn_mfma_f32_16x16x32_fp8_fp8(
                        af[k2], bfr[cf][k2], acc[rf][cf], 0, 0, 0);
        }
        __builtin_amdgcn_s_setprio(0);
    }

    // ===== Epilogue (R20-validated) =====
    // C frag layout: col = l15 (word), local row = rf*16 + kgrp*4 + e.
    // Image g = row/36 (boundaries 36/72/108 inside rf = 2,4,6 only).
    float mm[2][4];
#pragma unroll
    for (int cf = 0; cf < 2; ++cf)
#pragma unroll
        for (int g = 0; g < 4; ++g) mm[cf][g] = -3.4e38f;

#pragma unroll
    for (int cf = 0; cf < 2; ++cf)
#pragma unroll
        for (int rf = 0; rf < 9; ++rf)
#pragma unroll
            for (int e = 0; e < 4; ++e) {
                const int row0 = rf * 16 + e;          // compile-time
                const int g0 = row0 / 36;              // compile-time
                const int g1 = (row0 + 12) / 36;       // compile-time
                float v = acc[rf][cf][e];
                if (g0 == g1) {
                    mm[cf][g0] = fmaxf(mm[cf][g0], v);
                } else {                               // straddle: one runtime compare
                    int lr = row0 + 4 * kgrp;
                    if (lr >= g1 * 36) mm[cf][g1] = fmaxf(mm[cf][g1], v);
                    else               mm[cf][g0] = fmaxf(mm[cf][g0], v);
                }
            }

    const int i_cap = it * 4 + (wc >> 1);
    const int nw = s_l[i_cap];
    float sums[4];
#pragma unroll
    for (int g = 0; g < 4; ++g) {
        float sg = 0.0f;
#pragma unroll
        for (int cf = 0; cf < 2; ++cf) {
            float m = mm[cf][g];
            m = fmaxf(m, __shfl_xor(m, 16));   // combine the 4 kgrp row-subsets
            m = fmaxf(m, __shfl_xor(m, 32));
            int wv = (wc & 1) * 32 + cf * 16 + l15;
            if (wv < nw) sg += m;
        }
        sg += __shfl_xor(sg, 1);
        sg += __shfl_xor(sg, 2);
        sg += __shfl_xor(sg, 4);
        sg += __shfl_xor(sg, 8);
        sums[g] = sg;                          // valid in lanes l15==0
    }
    if (lane == 0) {
#pragma unroll
        for (int g = 0; g < 4; ++g) red2[wc][g] = sums[g];
    }
    __syncthreads();
    if ((wc & 1) == 0 && lane == 0) {
        const float inv = 1.0f / (float)nw;
#pragma unroll
        for (int g = 0; g < 4; ++g) {
            int j_img = jt * 4 + g;
            S[j_img * B_SZ + i_cap] = (red2[wc][g] + red2[wc + 1][g]) * inv;
        }
    }
}

// Contrastive loss over the 128x128 score matrix, single block (1024 thr)
__global__ __launch_bounds__(1024) void loss_kernel(
        const float* __restrict__ S, float* __restrict__ out) {
    __shared__ float diag[B_SZ];
    __shared__ float red[1024];
    int t = threadIdx.x;
    if (t < B_SZ) diag[t] = S[t * (B_SZ + 1)];
    __syncthreads();
    float acc = 0.0f;
    for (int idx = t; idx < B_SZ * B_SZ; idx += 1024) {
        int a = idx >> 7, b = idx & (B_SZ - 1);
        if (a != b) {
            float v = S[idx];
            acc += fmaxf(MARGIN + v - diag[a], 0.0f)
                 + fmaxf(MARGIN + v - diag[b], 0.0f);
        }
    }
    red[t] = acc;
    __syncthreads();
    for (int s = 512; s > 0; s >>= 1) {
        if (t < s) red[t] += red[t + s];
        __syncthreads();
    }
    if (t == 0) out[0] = red[0];
}

extern "C" void kernel_launch(void* const* d_in, const int* in_sizes, int n_in,
                              void* d_out, int out_size, void* d_ws, size_t ws_size,
                              hipStream_t stream) {
    const float* im  = (const float*)d_in[0];
    const float* s   = (const float*)d_in[1];
    const int*   s_l = (const int*)d_in[2];
    // d_in[3] (x) unused by the math

    const int n_im = B_SZ * R_SZ * D_SZ;    // 4,718,592 fp8 bytes (unpadded)
    const int n_s  = B_SZ * WP_SZ * D_SZ;   // 8,388,608 fp8 bytes (word-padded)

    unsigned char* imb = (unsigned char*)d_ws;
    unsigned char* sb  = imb + n_im;
    float* S = (float*)(sb + n_s);          // 128*128 floats

    const int ngran = (n_im + n_s) / 16;    // 16-B granules
    convert_fp8_kernel<<<(ngran + 255) / 256, 256, 0, stream>>>(im, s, imb, sb);

    scores_kernel<<<1024, 512, 0, stream>>>(imb, sb, s_l, S);

    loss_kernel<<<1, 1024, 0, stream>>>(S, (float*)d_out);
}

// Round 22
// 74.984 us; speedup vs baseline: 1.3122x; 1.3122x over previous
//
#include <hip/hip_runtime.h>
#include <hip/hip_bf16.h>
#include <stdint.h>

// Problem dims (fixed by reference setup_inputs)
#define B_SZ 128
#define R_SZ 36       // real regions per image -- NOT padded (4 imgs = 144 = 9 frags)
#define W_SZ 60       // real words per caption
#define WP_SZ 64      // padded words (dup word 59, masked in epilogue)
#define D_SZ 1024
#define MARGIN 0.2f

#define ATILE_B (144 * 64)        // 9216 B per A K-tile (4 images, unpadded)
#define BTILE_B (256 * 64)        // 16384 B per B K-tile
#define BUFB    (ATILE_B + BTILE_B) // 25600 B; dbuf = 51.2 KB

typedef __attribute__((ext_vector_type(4))) float f32x4;    // MFMA C/D frag
typedef __attribute__((ext_vector_type(2))) long longx2;    // one b128 = 2 fp8 frags

typedef __attribute__((address_space(3))) unsigned int lds_u32;
typedef const __attribute__((address_space(1))) unsigned int glb_u32;

__device__ __forceinline__ void gload16(const unsigned char* g, unsigned char* l) {
    __builtin_amdgcn_global_load_lds((glb_u32*)g, (lds_u32*)l, 16, 0, 0);
}

// fp32 -> fp8 e4m3 (HW cvt) + K2-INTERLEAVE (validated R14/R15/R20).
// A: 1:1, NO row padding (packed-region layout = original im layout).
// B: word rows padded 60->64 (dup row 59; masked in epilogue).
// Each 64-B K-block of a row stored as [granule g=kgrp][k2][8B]:
//   out byte g*16 + k2*8 + b  <=  original k = k2*32 + g*8 + b.
__global__ __launch_bounds__(256) void convert_fp8_kernel(
        const float* __restrict__ im, const float* __restrict__ s,
        unsigned char* __restrict__ imb, unsigned char* __restrict__ sb) {
    const int nA = B_SZ * R_SZ * 64;      // 294,912 16-B granules of A
    const int nB = B_SZ * WP_SZ * 64;     // 524,288 granules of B
    int i = blockIdx.x * 256 + threadIdx.x;
    const float* srcrow;
    unsigned char* dst;
    int gran;
    if (i < nA) {
        gran = i & 63;
        int row = i >> 6;                 // packed row = j*36 + r (original layout)
        srcrow = im + ((size_t)row << 10);
        dst = imb + (size_t)i * 16;
    } else {
        int i2 = i - nA;
        if (i2 >= nB) return;
        gran = i2 & 63;
        int row = i2 >> 6;
        int j = row >> 6, w = row & 63;
        int ws = w < W_SZ ? w : W_SZ - 1;
        srcrow = s + ((size_t)(j * W_SZ + ws) << 10);
        dst = sb + (size_t)i2 * 16;
    }
    const int kb = gran >> 2, g = gran & 3;
    uint4 o;
    unsigned int* op = (unsigned int*)&o;
#pragma unroll
    for (int q = 0; q < 4; ++q) {
        const int kq = kb * 64 + (q >> 1) * 32 + g * 8 + (q & 1) * 4;
        float4 v = *reinterpret_cast<const float4*>(srcrow + kq);
        int w32 = __builtin_amdgcn_cvt_pk_fp8_f32(v.x, v.y, 0, false);
        w32 = __builtin_amdgcn_cvt_pk_fp8_f32(v.z, v.w, w32, true);
        op[q] = (unsigned int)w32;
    }
    *reinterpret_cast<uint4*>(dst) = o;
}

// Fused GEMM + MISA epilogue, fp8-e4m3, UNPADDED M (R20-validated optimum):
// Block 144x256 (4 images x 36 packed regions x 4 captions), BK=64, 8 waves
// as 1M x 8N: each wave owns ALL 9 row-frags x 32 cols (acc[9][2] = 72 regs,
// mfma_f32_16x16x32_fp8_fp8). dbuf LDS 51.2 KB; __launch_bounds__(512,4).
// Validated pieces verbatim: k2-interleaved b128 frag reads, zero-conflict
// quarter-wave swizzle slot=(kgrp^((row>>1)&3))*16 (both-sides involution),
// one-window-per-tile schedule (reads -> stage -> MFMAs -> vmcnt(0) + single
// s_barrier), supertile XCD swizzle.
// Epilogue: image boundaries at rows 36/72/108 fall inside frags rf=2,4,6;
// row0=rf*16+e compile-time -> target image g0 compile-time, straddle
// resolved by ONE runtime compare (all mm[][] indices compile-time, rule 20).
// Per-caption word-sum spans a wave pair -> tiny LDS pair reduction.
__global__ __launch_bounds__(512, 4) void scores_kernel(
        const unsigned char* __restrict__ imb,    // [4608][1024] fp8 interleaved
        const unsigned char* __restrict__ sbp,    // [128][64][1024] fp8 interleaved
        const int* __restrict__ s_l,
        float* __restrict__ S)                    // [j][i]
{
    __shared__ __align__(16) unsigned char LDS[2 * BUFB];   // 51.2 KB
    __shared__ float red2[8][4];

    const int tid  = threadIdx.x;
    const int wc   = tid >> 6;        // 0..7 (N-split only)
    const int lane = tid & 63;
    const int l15  = lane & 15;
    const int kgrp = lane >> 4;       // 0..3

    // Supertile XCD swizzle (R10-validated)
    int bid = blockIdx.x;
    int k8  = bid & 7;                // XCD
    int w   = bid >> 3;               // 0..127 within XCD
    int jtg = w >> 5;                 // 0..3
    int sw  = w & 31;
    int it  = k8 * 4 + (sw >> 3);     // 0..31 (4 captions each)
    int jt  = jtg * 8 + (sw & 7);     // 0..31 (4 images = 144 packed rows each)

    // staging: chunk = 16 rows x 64 B; row-in-chunk = lane>>2, dest granule lane&3;
    // source granule = (lane&3) ^ h(row), h(row) = (row>>1)&3 = (lane>>3)&3
    const int drow = lane >> 2;
    const int sgr  = ((lane & 3) ^ ((lane >> 3) & 3)) * 16;

    // 25 1-KB chunks (A:9, B:16); wave w stages chunks {w, w+8, w+16, w+24} (c<25)
    const unsigned char* gsrc[4];
    int ldso[4];
#pragma unroll
    for (int si = 0; si < 4; ++si) {
        int c = wc + si * 8;
        if (c < 9) {          // A chunk: packed rows jt*144 + c*16 + drow
            gsrc[si] = imb + (size_t)(jt * 144 + c * 16 + drow) * 1024 + sgr;
            ldso[si] = c * 1024 + lane * 16;
        } else if (c < 25) {  // B chunk
            int b = c - 9;
            gsrc[si] = sbp + (size_t)(it * 256 + b * 16 + drow) * 1024 + sgr;
            ldso[si] = ATILE_B + b * 1024 + lane * 16;
        }
    }

    // ds_read addressing: row*64 + (kgrp ^ ((row>>1)&3))*16 (R15 zero-conflict)
    const int slot0 = (kgrp ^ ((l15 >> 1) & 3)) * 16;
    const int abase = l15 * 64 + slot0;               // + rf*1024
    int bbase[2];
#pragma unroll
    for (int cf = 0; cf < 2; ++cf)
        bbase[cf] = ATILE_B + (wc * 32 + cf * 16 + l15) * 64 + slot0;

    f32x4 acc[9][2] = {};

    // prologue: stage tile 0 into buffer 0
#pragma unroll
    for (int si = 0; si < 4; ++si) {
        int c = wc + si * 8;
        if (c < 25) gload16(gsrc[si], LDS + ldso[si]);
    }
    asm volatile("s_waitcnt vmcnt(0)" ::: "memory");
    __builtin_amdgcn_s_barrier();

#pragma unroll 2
    for (int kt = 0; kt < 16; ++kt) {
        const int cur = kt & 1;
        const unsigned char* base = LDS + cur * BUFB;

        // B frags for this wave's 32 cols: 2 ds_read_b128
        longx2 bfr[2];
#pragma unroll
        for (int cf = 0; cf < 2; ++cf)
            bfr[cf] = *reinterpret_cast<const longx2*>(base + bbase[cf]);

        // stage tile kt+1 into the other buffer (R15/R20 placement)
        if (kt < 15) {
            const int ko = (kt + 1) * 64;
            unsigned char* dstb = LDS + (cur ^ 1) * BUFB;
#pragma unroll
            for (int si = 0; si < 4; ++si) {
                int c = wc + si * 8;
                if (c < 25) gload16(gsrc[si] + ko, dstb + ldso[si]);
            }
        }

        // A streamed per rf: 1 ds_read_b128 + 4 MFMAs (keeps liveness low)
        __builtin_amdgcn_s_setprio(1);
#pragma unroll
        for (int rf = 0; rf < 9; ++rf) {
            longx2 af = *reinterpret_cast<const longx2*>(base + abase + rf * 1024);
#pragma unroll
            for (int k2 = 0; k2 < 2; ++k2)
#pragma unroll
                for (int cf = 0; cf < 2; ++cf)
                    acc[rf][cf] = __builtin_amdgcn_mfma_f32_16x16x32_fp8_fp8(
                        af[k2], bfr[cf][k2], acc[rf][cf], 0, 0, 0);
        }
        __builtin_amdgcn_s_setprio(0);

        if (kt < 15) {
            asm volatile("s_waitcnt vmcnt(0)" ::: "memory");  // tile kt+1 staged
            __builtin_amdgcn_s_barrier();                     // dbuf handoff
        }
    }

    // ===== Epilogue =====
    // C frag layout (validated): col = l15 (word), local row = rf*16 + kgrp*4 + e.
    // Image g = row/36 (boundaries 36/72/108 inside rf = 2,4,6 only).
    float mm[2][4];
#pragma unroll
    for (int cf = 0; cf < 2; ++cf)
#pragma unroll
        for (int g = 0; g < 4; ++g) mm[cf][g] = -3.4e38f;

#pragma unroll
    for (int cf = 0; cf < 2; ++cf)
#pragma unroll
        for (int rf = 0; rf < 9; ++rf)
#pragma unroll
            for (int e = 0; e < 4; ++e) {
                const int row0 = rf * 16 + e;          // compile-time
                const int g0 = row0 / 36;              // compile-time
                const int g1 = (row0 + 12) / 36;       // compile-time
                float v = acc[rf][cf][e];
                if (g0 == g1) {
                    mm[cf][g0] = fmaxf(mm[cf][g0], v);
                } else {                               // straddle: one runtime compare
                    int lr = row0 + 4 * kgrp;
                    if (lr >= g1 * 36) mm[cf][g1] = fmaxf(mm[cf][g1], v);
                    else               mm[cf][g0] = fmaxf(mm[cf][g0], v);
                }
            }

    const int i_cap = it * 4 + (wc >> 1);
    const int nw = s_l[i_cap];
    float sums[4];
#pragma unroll
    for (int g = 0; g < 4; ++g) {
        float sg = 0.0f;
#pragma unroll
        for (int cf = 0; cf < 2; ++cf) {
            float m = mm[cf][g];
            m = fmaxf(m, __shfl_xor(m, 16));   // combine the 4 kgrp row-subsets
            m = fmaxf(m, __shfl_xor(m, 32));
            int wv = (wc & 1) * 32 + cf * 16 + l15;
            if (wv < nw) sg += m;
        }
        sg += __shfl_xor(sg, 1);
        sg += __shfl_xor(sg, 2);
        sg += __shfl_xor(sg, 4);
        sg += __shfl_xor(sg, 8);
        sums[g] = sg;                          // valid in lanes l15==0
    }
    if (lane == 0) {
#pragma unroll
        for (int g = 0; g < 4; ++g) red2[wc][g] = sums[g];
    }
    __syncthreads();
    if ((wc & 1) == 0 && lane == 0) {
        const float inv = 1.0f / (float)nw;
#pragma unroll
        for (int g = 0; g < 4; ++g) {
            int j_img = jt * 4 + g;
            S[j_img * B_SZ + i_cap] = (red2[wc][g] + red2[wc + 1][g]) * inv;
        }
    }
}

// Contrastive loss over the 128x128 score matrix, single block (1024 thr)
__global__ __launch_bounds__(1024) void loss_kernel(
        const float* __restrict__ S, float* __restrict__ out) {
    __shared__ float diag[B_SZ];
    __shared__ float red[1024];
    int t = threadIdx.x;
    if (t < B_SZ) diag[t] = S[t * (B_SZ + 1)];
    __syncthreads();
    float acc = 0.0f;
    for (int idx = t; idx < B_SZ * B_SZ; idx += 1024) {
        int a = idx >> 7, b = idx & (B_SZ - 1);
        if (a != b) {
            float v = S[idx];
            acc += fmaxf(MARGIN + v - diag[a], 0.0f)
                 + fmaxf(MARGIN + v - diag[b], 0.0f);
        }
    }
    red[t] = acc;
    __syncthreads();
    for (int s = 512; s > 0; s >>= 1) {
        if (t < s) red[t] += red[t + s];
        __syncthreads();
    }
    if (t == 0) out[0] = red[0];
}

extern "C" void kernel_launch(void* const* d_in, const int* in_sizes, int n_in,
                              void* d_out, int out_size, void* d_ws, size_t ws_size,
                              hipStream_t stream) {
    const float* im  = (const float*)d_in[0];
    const float* s   = (const float*)d_in[1];
    const int*   s_l = (const int*)d_in[2];
    // d_in[3] (x) unused by the math

    const int n_im = B_SZ * R_SZ * D_SZ;    // 4,718,592 fp8 bytes (unpadded)
    const int n_s  = B_SZ * WP_SZ * D_SZ;   // 8,388,608 fp8 bytes (word-padded)

    unsigned char* imb = (unsigned char*)d_ws;
    unsigned char* sb  = imb + n_im;
    float* S = (float*)(sb + n_s);          // 128*128 floats

    const int ngran = (n_im + n_s) / 16;    // 16-B granules
    convert_fp8_kernel<<<(ngran + 255) / 256, 256, 0, stream>>>(im, s, imb, sb);

    scores_kernel<<<1024, 512, 0, stream>>>(imb, sb, s_l, S);

    loss_kernel<<<1, 1024, 0, stream>>>(S, (float*)d_out);
}